// Round 3
// baseline (2776.192 us; speedup 1.0000x reference)
//
#include <hip/hip_runtime.h>
#include <hip/hip_bf16.h>

typedef __hip_bfloat16 bf16;

#define BB 32   // batch
#define NN 16   // patches / backbones

__device__ __forceinline__ float b2f(bf16 v){ return __bfloat162float(v); }
__device__ __forceinline__ bf16  f2b(float v){ return __float2bfloat16(v); }
__device__ __forceinline__ float ldv(const float* p){ return *p; }
__device__ __forceinline__ float ldv(const bf16* p){ return b2f(*p); }
__device__ __forceinline__ void  stv(float* p, float v){ *p = v; }
__device__ __forceinline__ void  stv(bf16* p, float v){ *p = f2b(v); }

// ---------------------------------------------------------------------------
// dtype probe: bf16 N(0,1) data never has exponent==0xFF; f32 data read as
// u16 halves virtually always does. flag=1 -> float32 inputs; 0 -> bf16.
// ---------------------------------------------------------------------------
__launch_bounds__(256)
__global__ void detect_ker(const unsigned short* __restrict__ xs, int* __restrict__ flag)
{
    int tid = threadIdx.x;
    int cnt = 0;
    for (int i = tid; i < 262144; i += 256) {
        unsigned short u = xs[i];
        if ((u & 0x7F80u) == 0x7F80u) cnt++;
    }
    #pragma unroll
    for (int off = 32; off > 0; off >>= 1) cnt += __shfl_down(cnt, off, 64);
    __shared__ int red[4];
    if ((tid & 63) == 0) red[tid >> 6] = cnt;
    __syncthreads();
    if (tid == 0) flag[0] = (red[0] + red[1] + red[2] + red[3]) > 0 ? 1 : 0;
}

// ---------------------------------------------------------------------------
// stage all inputs into a contiguous FLOAT arena (upconvert bf16 if needed)
// ---------------------------------------------------------------------------
struct CvtArgs { const void* src[19]; int cnt[19]; int off[19]; };

__launch_bounds__(256)
__global__ void convert_ker(CvtArgs a, float* __restrict__ dst, const int* __restrict__ flag)
{
    const int which = blockIdx.y;
    const int cnt = a.cnt[which];
    if ((int)blockIdx.x * 2048 >= cnt) return;
    const int base = blockIdx.x * 2048 + threadIdx.x;
    float* d = dst + a.off[which];
    if (*flag) {
        const float* s = (const float*)a.src[which];
        #pragma unroll
        for (int k = 0; k < 8; ++k) { int j = base + k * 256; if (j < cnt) d[j] = s[j]; }
    } else {
        const bf16* s = (const bf16*)a.src[which];
        #pragma unroll
        for (int k = 0; k < 8; ++k) { int j = base + k * 256; if (j < cnt) d[j] = b2f(s[j]); }
    }
}

// ---------------------------------------------------------------------------
// conv0 forward (recompute-only) + per-channel sum/sumsq atomics.
// accum[0..511]=sum, accum[512..1023]=sumsq per (n*16+c).
// ---------------------------------------------------------------------------
__launch_bounds__(256)
__global__ void conv0stats_ker(const float* __restrict__ x, const float* __restrict__ w,
                               float* __restrict__ accum)
{
    constexpr int STRIP = 8, STRIPS = 8, IN_ROWS = 10, TW = 66;
    __shared__ float tile[3][IN_ROWS][TW];
    const int tid = threadIdx.x;
    const int bid = blockIdx.x;
    const int s = bid % STRIPS;
    const int b = (bid / STRIPS) % BB;
    const int n = bid / (STRIPS * BB);
    const int pr = (n >> 2) * 64, pc = (n & 3) * 64;
    const int r0 = s * STRIP - 1;

    for (int idx = tid; idx < 3 * IN_ROWS * TW; idx += 256) {
        int ci = idx / (IN_ROWS * TW);
        int rem = idx - ci * (IN_ROWS * TW);
        int rr = rem / TW, cc = rem - rr * TW;
        int gr = r0 + rr, gc = cc - 1;
        float v = 0.f;
        if (gr >= 0 && gr < 64 && gc >= 0 && gc < 64)
            v = x[((size_t)(b * 3 + ci) * 256 + (pr + gr)) * 256 + (pc + gc)];
        tile[ci][rr][cc] = v;
    }
    __syncthreads();

    const int xo = tid & 63;
    const int cq = tid >> 6;
    for (int pass = 0; pass < 2; ++pass) {
        const int co = (pass * 4 + cq) * 2;
        const float* wb = w + (size_t)((n * 16 + co) * 3) * 9;
        float acc0[STRIP], acc1[STRIP];
        #pragma unroll
        for (int r = 0; r < STRIP; ++r) { acc0[r] = 0.f; acc1[r] = 0.f; }
        #pragma unroll
        for (int ci = 0; ci < 3; ++ci) {
            float w0[9], w1[9];
            #pragma unroll
            for (int j = 0; j < 9; ++j) {
                w0[j] = wb[ci * 9 + j];
                w1[j] = wb[(3 + ci) * 9 + j];
            }
            float win[3][3];
            #pragma unroll
            for (int c0 = 0; c0 < 3; ++c0) {
                win[0][c0] = tile[ci][0][xo + c0];
                win[1][c0] = tile[ci][1][xo + c0];
            }
            #pragma unroll
            for (int ry = 0; ry < STRIP; ++ry) {
                #pragma unroll
                for (int c0 = 0; c0 < 3; ++c0)
                    win[(ry + 2) % 3][c0] = tile[ci][ry + 2][xo + c0];
                #pragma unroll
                for (int ky = 0; ky < 3; ++ky)
                    #pragma unroll
                    for (int kx = 0; kx < 3; ++kx) {
                        float v = win[(ry + ky) % 3][kx];
                        acc0[ry] = fmaf(v, w0[ky * 3 + kx], acc0[ry]);
                        acc1[ry] = fmaf(v, w1[ky * 3 + kx], acc1[ry]);
                    }
            }
        }
        float s0 = 0.f, q0 = 0.f, s1 = 0.f, q1 = 0.f;
        #pragma unroll
        for (int r = 0; r < STRIP; ++r) {
            s0 += acc0[r]; q0 = fmaf(acc0[r], acc0[r], q0);
            s1 += acc1[r]; q1 = fmaf(acc1[r], acc1[r], q1);
        }
        #pragma unroll
        for (int off = 32; off > 0; off >>= 1) {
            s0 += __shfl_down(s0, off, 64); q0 += __shfl_down(q0, off, 64);
            s1 += __shfl_down(s1, off, 64); q1 += __shfl_down(q1, off, 64);
        }
        if (xo == 0) {
            atomicAdd(&accum[n * 16 + co],       s0);
            atomicAdd(&accum[512 + n * 16 + co], q0);
            atomicAdd(&accum[n * 16 + co + 1],       s1);
            atomicAdd(&accum[512 + n * 16 + co + 1], q1);
        }
    }
}

__launch_bounds__(256)
__global__ void coef0fin_ker(const float* __restrict__ accum, const float* __restrict__ hw,
                             float* __restrict__ coef)
{
    int i = threadIdx.x;            // n*16+c
    const float cnt = 131072.f;     // B * 64 * 64
    float mu = accum[i] / cnt;
    float var = fmaxf(accum[512 + i] / cnt - mu * mu, 0.f);
    float rs = rsqrtf(var + 1e-5f);
    int n = i >> 4, c = i & 15;
    float w0 = hw[(n * 3 + 0) * 16 + c];
    float w1 = hw[(n * 3 + 1) * 16 + c];
    float w2 = hw[(n * 3 + 2) * 16 + c];
    float c2 = w2 * 0.70710678118654752440f;
    coef[i * 3 + 0] = (w0 - c2) - w1 * rs * mu + c2 * rs * rs * mu * mu;
    coef[i * 3 + 1] = w1 * rs - 2.f * c2 * rs * rs * mu;
    coef[i * 3 + 2] = c2 * rs * rs;
}

// ---------------------------------------------------------------------------
// fused stage0+1: recompute conv0 tile from x (LDS), herpn(coef0), conv1 -> a1
// ---------------------------------------------------------------------------
template<typename TO>
__launch_bounds__(256)
__global__ void fused01_ker(const float* __restrict__ x, const float* __restrict__ w0g,
                            const float* __restrict__ coef, const float* __restrict__ w1g,
                            TO* __restrict__ aout)
{
    constexpr int STRIPS = 8;
    __shared__ float xt[3][12][68];
    __shared__ float a0t[16][10][66];
    __shared__ float wt[16 * 27];
    __shared__ float cfA[16], cfB[16], cfC[16];

    const int tid = threadIdx.x;
    const int bid = blockIdx.x;
    const int s = bid % STRIPS;
    const int b = (bid / STRIPS) % BB;
    const int n = bid / (STRIPS * BB);
    const int pr = (n >> 2) * 64, pc = (n & 3) * 64;

    if (tid < 16) {
        cfA[tid] = coef[(n * 16 + tid) * 3 + 0];
        cfB[tid] = coef[(n * 16 + tid) * 3 + 1];
        cfC[tid] = coef[(n * 16 + tid) * 3 + 2];
    }
    for (int i = tid; i < 16 * 27; i += 256) wt[i] = w0g[(size_t)n * 432 + i];

    const int rx0 = s * 8 - 2;
    for (int idx = tid; idx < 3 * 12 * 68; idx += 256) {
        int ci = idx / 816;
        int rem = idx - ci * 816;
        int rr = rem / 68, cc = rem - rr * 68;
        int gr = rx0 + rr, gc = cc - 2;
        float v = 0.f;
        if (gr >= 0 && gr < 64 && gc >= 0 && gc < 64)
            v = x[((size_t)(b * 3 + ci) * 256 + (pr + gr)) * 256 + (pc + gc)];
        xt[ci][rr][cc] = v;
    }
    __syncthreads();

    // herpn(conv0) tile; cells outside the 64x64 patch are conv1's zero pad
    for (int idx = tid; idx < 16 * 10 * 66; idx += 256) {
        int c = idx / 660;
        int rem = idx - c * 660;
        int rr = rem / 66, cc = rem - rr * 66;
        int gr = s * 8 - 1 + rr, gc = cc - 1;
        float v = 0.f;
        if (gr >= 0 && gr < 64 && gc >= 0 && gc < 64) {
            float acc = 0.f;
            const float* wp = &wt[c * 27];
            #pragma unroll
            for (int ci = 0; ci < 3; ++ci)
                #pragma unroll
                for (int ky = 0; ky < 3; ++ky)
                    #pragma unroll
                    for (int kx = 0; kx < 3; ++kx)
                        acc = fmaf(xt[ci][rr + ky][cc + kx], wp[ci * 9 + ky * 3 + kx], acc);
            v = fmaf(acc, fmaf(acc, cfC[c], cfB[c]), cfA[c]);
        }
        a0t[c][rr][cc] = v;
    }
    __syncthreads();

    const int xo = tid & 63;
    const int cq = tid >> 6;
    for (int pass = 0; pass < 2; ++pass) {
        const int co = (pass * 4 + cq) * 2;
        const float* wb = w1g + (size_t)((n * 16 + co) * 16) * 9;
        float acc0[8], acc1[8];
        #pragma unroll
        for (int r = 0; r < 8; ++r) { acc0[r] = 0.f; acc1[r] = 0.f; }
        for (int ci = 0; ci < 16; ++ci) {
            float w0[9], w1[9];
            #pragma unroll
            for (int j = 0; j < 9; ++j) {
                w0[j] = wb[ci * 9 + j];
                w1[j] = wb[(16 + ci) * 9 + j];
            }
            float win[3][3];
            #pragma unroll
            for (int c0 = 0; c0 < 3; ++c0) {
                win[0][c0] = a0t[ci][0][xo + c0];
                win[1][c0] = a0t[ci][1][xo + c0];
            }
            #pragma unroll
            for (int ry = 0; ry < 8; ++ry) {
                #pragma unroll
                for (int c0 = 0; c0 < 3; ++c0)
                    win[(ry + 2) % 3][c0] = a0t[ci][ry + 2][xo + c0];
                #pragma unroll
                for (int ky = 0; ky < 3; ++ky)
                    #pragma unroll
                    for (int kx = 0; kx < 3; ++kx) {
                        float v = win[(ry + ky) % 3][kx];
                        acc0[ry] = fmaf(v, w0[ky * 3 + kx], acc0[ry]);
                        acc1[ry] = fmaf(v, w1[ky * 3 + kx], acc1[ry]);
                    }
            }
        }
        TO* ob = aout + (size_t)((n * BB + b) * 16 + co) * 4096 + (s * 8) * 64 + xo;
        #pragma unroll
        for (int ry = 0; ry < 8; ++ry) {
            stv(&ob[ry * 64], acc0[ry]);
            stv(&ob[4096 + ry * 64], acc1[ry]);
        }
    }
}

// ---------------------------------------------------------------------------
// stats: per (n,c) mean/var over [B,HW]; fold HerPN into quadratic coef.
// ---------------------------------------------------------------------------
template<typename TI, int C, int HW>
__launch_bounds__(256)
__global__ void stats_ker(const TI* __restrict__ a, const float* __restrict__ hw,
                          float* __restrict__ coef)
{
    const int tid = threadIdx.x;
    const int n = blockIdx.x / C, c = blockIdx.x % C;
    float s = 0.f, s2 = 0.f;
    for (int b = 0; b < BB; ++b) {
        const TI* p = a + (size_t)((n * BB + b) * C + c) * HW;
        for (int i = tid; i < HW; i += 256) {
            float v = ldv(&p[i]);
            s += v;
            s2 = fmaf(v, v, s2);
        }
    }
    #pragma unroll
    for (int off = 32; off > 0; off >>= 1) {
        s  += __shfl_down(s, off, 64);
        s2 += __shfl_down(s2, off, 64);
    }
    __shared__ float red[8];
    int wid = tid >> 6, lane = tid & 63;
    if (lane == 0) { red[wid] = s; red[4 + wid] = s2; }
    __syncthreads();
    if (tid == 0) {
        s  = red[0] + red[1] + red[2] + red[3];
        s2 = red[4] + red[5] + red[6] + red[7];
        const float cnt = (float)(BB * HW);
        float mu = s / cnt;
        float var = fmaxf(s2 / cnt - mu * mu, 0.f);
        float rs = rsqrtf(var + 1e-5f);
        float w0 = hw[(n * 3 + 0) * C + c];
        float w1 = hw[(n * 3 + 1) * C + c];
        float w2 = hw[(n * 3 + 2) * C + c];
        float c2 = w2 * 0.70710678118654752440f;
        coef[(n * C + c) * 3 + 0] = (w0 - c2) - w1 * rs * mu + c2 * rs * rs * mu * mu;
        coef[(n * C + c) * 3 + 1] = w1 * rs - 2.f * c2 * rs * rs * mu;
        coef[(n * C + c) * 3 + 2] = c2 * rs * rs;
    }
}

// ---------------------------------------------------------------------------
// generic fused herpn+conv3x3
// ---------------------------------------------------------------------------
template<typename TI, typename TO, int CIN, int COUT, int WIN, int WOUT, int STRIDE, int STRIP>
__launch_bounds__(256)
__global__ void conv_ker(const TI* __restrict__ ain, const float* __restrict__ coef,
                         const float* __restrict__ w, TO* __restrict__ aout)
{
    constexpr int HIN = WIN, HOUT = WOUT;
    constexpr int STRIPS = HOUT / STRIP;
    constexpr int IN_ROWS = STRIDE * (STRIP - 1) + 3;
    constexpr int TW = WIN + 2;
    constexpr int CQ = 256 / WOUT;
    constexpr int TCO = 2;
    constexpr int PASSES = COUT / (CQ * TCO);

    __shared__ float tile[CIN][IN_ROWS][TW];
    __shared__ float cfA[CIN], cfB[CIN], cfC[CIN];

    const int tid = threadIdx.x;
    const int bid = blockIdx.x;
    const int s = bid % STRIPS;
    const int b = (bid / STRIPS) % BB;
    const int n = bid / (STRIPS * BB);

    if (tid < CIN) {
        cfA[tid] = coef[(n * CIN + tid) * 3 + 0];
        cfB[tid] = coef[(n * CIN + tid) * 3 + 1];
        cfC[tid] = coef[(n * CIN + tid) * 3 + 2];
    }
    __syncthreads();

    const int r0 = s * STRIP * STRIDE - 1;
    const TI* abase = ain + (size_t)(n * BB + b) * CIN * HIN * WIN;
    for (int idx = tid; idx < CIN * IN_ROWS * TW; idx += 256) {
        int ci = idx / (IN_ROWS * TW);
        int rem = idx - ci * (IN_ROWS * TW);
        int rr = rem / TW;
        int cc = rem - rr * TW;
        int gr = r0 + rr, gc = cc - 1;
        float v = 0.f;
        if (gr >= 0 && gr < HIN && gc >= 0 && gc < WIN) {
            float raw = ldv(&abase[(size_t)ci * HIN * WIN + gr * WIN + gc]);
            v = fmaf(raw, fmaf(raw, cfC[ci], cfB[ci]), cfA[ci]);
        }
        tile[ci][rr][cc] = v;
    }
    __syncthreads();

    const int xo = tid % WOUT;
    const int cq = tid / WOUT;
    #pragma unroll
    for (int pass = 0; pass < PASSES; ++pass) {
        const int co = (pass * CQ + cq) * TCO;
        const float* wb = w + (size_t)((n * COUT + co) * CIN) * 9;
        float acc0[STRIP], acc1[STRIP];
        #pragma unroll
        for (int r = 0; r < STRIP; ++r) { acc0[r] = 0.f; acc1[r] = 0.f; }
        for (int ci = 0; ci < CIN; ++ci) {
            float w0[9], w1[9];
            #pragma unroll
            for (int j = 0; j < 9; ++j) {
                w0[j] = wb[ci * 9 + j];
                w1[j] = wb[(CIN + ci) * 9 + j];
            }
            if (STRIDE == 1) {
                float win[3][3];
                #pragma unroll
                for (int c0 = 0; c0 < 3; ++c0) {
                    win[0][c0] = tile[ci][0][xo + c0];
                    win[1][c0] = tile[ci][1][xo + c0];
                }
                #pragma unroll
                for (int ry = 0; ry < STRIP; ++ry) {
                    #pragma unroll
                    for (int c0 = 0; c0 < 3; ++c0)
                        win[(ry + 2) % 3][c0] = tile[ci][ry + 2][xo + c0];
                    #pragma unroll
                    for (int ky = 0; ky < 3; ++ky)
                        #pragma unroll
                        for (int kx = 0; kx < 3; ++kx) {
                            float v = win[(ry + ky) % 3][kx];
                            acc0[ry] = fmaf(v, w0[ky * 3 + kx], acc0[ry]);
                            acc1[ry] = fmaf(v, w1[ky * 3 + kx], acc1[ry]);
                        }
                }
            } else {
                #pragma unroll
                for (int ry = 0; ry < STRIP; ++ry)
                    #pragma unroll
                    for (int ky = 0; ky < 3; ++ky)
                        #pragma unroll
                        for (int kx = 0; kx < 3; ++kx) {
                            float v = tile[ci][ry * 2 + ky][xo * 2 + kx];
                            acc0[ry] = fmaf(v, w0[ky * 3 + kx], acc0[ry]);
                            acc1[ry] = fmaf(v, w1[ky * 3 + kx], acc1[ry]);
                        }
            }
        }
        TO* ob = aout + (size_t)((n * BB + b) * COUT + co) * HOUT * WOUT
                 + (s * STRIP) * WOUT + xo;
        #pragma unroll
        for (int ry = 0; ry < STRIP; ++ry) {
            stv(&ob[ry * WOUT], acc0[ry]);
            stv(&ob[HOUT * WOUT + ry * WOUT], acc1[ry]);
        }
    }
}

// ---------------------------------------------------------------------------
// pool: herpn(a5) -> quadrant means -> y[N,B,256] (fp32)
// ---------------------------------------------------------------------------
template<typename TI>
__launch_bounds__(256)
__global__ void pool_ker(const TI* __restrict__ a5, const float* __restrict__ coef,
                         float* __restrict__ y)
{
    const int n = blockIdx.x / BB, b = blockIdx.x % BB;
    const int f = threadIdx.x;
    const int c = f >> 2, qh = (f >> 1) & 1, qw = f & 1;
    const TI* p = a5 + (size_t)((n * BB + b) * 64 + c) * 256;
    float A = coef[(n * 64 + c) * 3 + 0];
    float Bc = coef[(n * 64 + c) * 3 + 1];
    float Cc = coef[(n * 64 + c) * 3 + 2];
    float ssum = 0.f;
    for (int iy = 0; iy < 8; ++iy)
        for (int ix = 0; ix < 8; ++ix) {
            float raw = ldv(&p[(qh * 8 + iy) * 16 + (qw * 8 + ix)]);
            ssum += fmaf(raw, fmaf(raw, Cc, Bc), A);
        }
    y[(size_t)(n * BB + b) * 256 + f] = ssum * (1.f / 64.f);
}

__launch_bounds__(256)
__global__ void bn1_ker(const float* __restrict__ y, const float* __restrict__ g,
                        const float* __restrict__ bta, float* __restrict__ ybn)
{
    const int gid = blockIdx.x * 256 + threadIdx.x;   // n*256 + f
    const int n = gid >> 8, f = gid & 255;
    float s = 0.f, s2 = 0.f;
    for (int b = 0; b < BB; ++b) {
        float v = y[(size_t)((n * BB + b) * 256) + f];
        s += v;
        s2 = fmaf(v, v, s2);
    }
    float mu = s * (1.f / BB);
    float var = fmaxf(s2 * (1.f / BB) - mu * mu, 0.f);
    float rs = rsqrtf(var + 1e-5f);
    float gg = g[(n << 8) + f];
    float bb = bta[(n << 8) + f];
    for (int b = 0; b < BB; ++b) {
        float v = y[(size_t)((n * BB + b) * 256) + f];
        ybn[(size_t)((n * BB + b) * 256) + f] = fmaf((v - mu) * rs, gg, bb);
    }
}

// ---------------------------------------------------------------------------
// head: per-b GEMV (wave-per-row, lane-split K) + jigsaw pred
// ---------------------------------------------------------------------------
__launch_bounds__(256)
__global__ void head_ker(const float* __restrict__ ybn, const float* __restrict__ lin_w,
                         const float* __restrict__ lin_b, const float* __restrict__ jig_w,
                         const float* __restrict__ jig_b, float* __restrict__ ograw,
                         void* __restrict__ d_out, const int* __restrict__ flag)
{
    __shared__ float sy[4096];
    const int b = blockIdx.x;
    const int tid = threadIdx.x;
    for (int idx = tid; idx < 4096; idx += 256) {
        int n = idx >> 8, f = idx & 255;
        sy[idx] = ybn[(size_t)((n * BB + b) * 256) + f];
    }
    __syncthreads();
    const int wv = tid >> 6, ln = tid & 63;
    const bool isf32 = (*flag != 0);
    // og_raw[b][j]
    for (int j = wv; j < 256; j += 4) {
        const float* wrow = lin_w + (size_t)j * 4096;
        float a = 0.f;
        for (int i = ln; i < 4096; i += 64)
            a = fmaf(sy[i], wrow[i], a);
        #pragma unroll
        for (int off = 32; off > 0; off >>= 1) a += __shfl_down(a, off, 64);
        if (ln == 0) ograw[b * 256 + j] = a + lin_b[j];
    }
    // pred[b][n][k]
    for (int o = wv; o < 256; o += 4) {
        const int nn = o >> 4, k = o & 15;
        const float* wrow = jig_w + k * 256;
        const float* srow = sy + nn * 256;
        float p = 0.f;
        for (int f = ln; f < 256; f += 64)
            p = fmaf(srow[f], wrow[f], p);
        #pragma unroll
        for (int off = 32; off > 0; off >>= 1) p += __shfl_down(p, off, 64);
        if (ln == 0) {
            float v = p + jig_b[k];
            int pidx = 8192 + (b * 16 + nn) * 16 + k;
            if (isf32) ((float*)d_out)[pidx] = v;
            else       ((bf16*)d_out)[pidx] = f2b(v);
        }
    }
}

__launch_bounds__(256)
__global__ void ogbn_ker(const float* __restrict__ ograw, void* __restrict__ d_out,
                         const int* __restrict__ flag)
{
    const int j = threadIdx.x;
    float s = 0.f, s2 = 0.f;
    for (int b = 0; b < BB; ++b) {
        float v = ograw[b * 256 + j];
        s += v;
        s2 = fmaf(v, v, s2);
    }
    float mu = s * (1.f / BB);
    float var = fmaxf(s2 * (1.f / BB) - mu * mu, 0.f);
    float rs = rsqrtf(var + 1e-5f);
    const bool isf32 = (*flag != 0);
    for (int b = 0; b < BB; ++b) {
        float v = (ograw[b * 256 + j] - mu) * rs;
        if (isf32) ((float*)d_out)[b * 256 + j] = v;
        else       ((bf16*)d_out)[b * 256 + j] = f2b(v);
    }
    float t = (float)(j & 15);
    if (isf32) { ((float*)d_out)[16384 + j] = t; ((float*)d_out)[16640 + j] = t; }
    else       { ((bf16*)d_out)[16384 + j] = f2b(t); ((bf16*)d_out)[16640 + j] = f2b(t); }
}

// ---------------------------------------------------------------------------
extern "C" void kernel_launch(void* const* d_in, const int* in_sizes, int n_in,
                              void* d_out, int out_size, void* d_ws, size_t ws_size,
                              hipStream_t stream)
{
    char* wsb = (char*)d_ws;
    int*   flag  = (int*)wsb;                       // @0
    float* accum = (float*)(wsb + 4096);            // 1024 f
    float* coefs = (float*)(wsb + 16384);           // 6*3072 f
    float* y     = (float*)(wsb + 98304);           // 131072 f
    float* ybn   = (float*)(wsb + 622592);          // 131072 f
    float* ograw = (float*)(wsb + 1146880);         // 8192 f
    float* staged = (float*)(wsb + 1310720);        // f32 arena: 8,513,040 floats

    CvtArgs ca;
    int off = 0, maxc = 0;
    for (int i = 0; i < 19; ++i) {
        ca.src[i] = d_in[i];
        ca.cnt[i] = in_sizes[i];
        ca.off[i] = off;
        off += in_sizes[i];
        if (in_sizes[i] > maxc) maxc = in_sizes[i];
    }
    float* sx      = staged + ca.off[0];
    float* scw0    = staged + ca.off[1];
    float* shw1    = staged + ca.off[2];
    float* scw1    = staged + ca.off[3];
    float* shw2    = staged + ca.off[4];
    float* scw2    = staged + ca.off[5];
    float* shw3    = staged + ca.off[6];
    float* scw3    = staged + ca.off[7];
    float* shw4    = staged + ca.off[8];
    float* scw4    = staged + ca.off[9];
    float* shw5    = staged + ca.off[10];
    float* scw5    = staged + ca.off[11];
    float* spool   = staged + ca.off[12];
    float* sg      = staged + ca.off[13];
    float* sb      = staged + ca.off[14];
    float* slin_w  = staged + ca.off[15];
    float* slin_b  = staged + ca.off[16];
    float* sjig_w  = staged + ca.off[17];
    float* sjig_b  = staged + ca.off[18];

    float* coef0 = coefs + 0 * 3072;
    float* coef1 = coefs + 1 * 3072;
    float* coef2 = coefs + 2 * 3072;
    float* coef3 = coefs + 3 * 3072;
    float* coef4 = coefs + 4 * 3072;
    float* coef5 = coefs + 5 * 3072;

    size_t stagedEnd = 1310720ull + (size_t)off * 4ull;
    size_t r1off = (stagedEnd + (1ull << 20)) & ~((1ull << 20) - 1ull);
    const bool planA = ws_size >= r1off + (128ull << 20) + (64ull << 20);

    detect_ker<<<1, 256, 0, stream>>>((const unsigned short*)d_in[0], flag);
    convert_ker<<<dim3((maxc + 2047) / 2048, 19), 256, 0, stream>>>(ca, staged, flag);

    hipMemsetAsync(accum, 0, 1024 * sizeof(float), stream);
    conv0stats_ker<<<NN * BB * 8, 256, 0, stream>>>(sx, scw0, accum);
    coef0fin_ker<<<1, 256, 0, stream>>>(accum, shw1, coef0);

    if (planA) {
        float* a1 = (float*)(wsb + r1off);                      // 128 MiB region
        float* a2 = (float*)(wsb + r1off + (128ull << 20));     // 64 MiB region
        float* a3 = a1;
        float* a4 = a2;
        float* a5 = a1;

        fused01_ker<float><<<NN * BB * 8, 256, 0, stream>>>(sx, scw0, coef0, scw1, a1);
        stats_ker<float, 16, 4096><<<NN * 16, 256, 0, stream>>>(a1, shw2, coef1);
        conv_ker<float, float, 16, 32, 64, 32, 2, 4><<<NN * BB * 8, 256, 0, stream>>>(a1, coef1, scw2, a2);
        stats_ker<float, 32, 1024><<<NN * 32, 256, 0, stream>>>(a2, shw3, coef2);
        conv_ker<float, float, 32, 32, 32, 32, 1, 8><<<NN * BB * 4, 256, 0, stream>>>(a2, coef2, scw3, a3);
        stats_ker<float, 32, 1024><<<NN * 32, 256, 0, stream>>>(a3, shw4, coef3);
        conv_ker<float, float, 32, 64, 32, 16, 2, 4><<<NN * BB * 4, 256, 0, stream>>>(a3, coef3, scw4, a4);
        stats_ker<float, 64, 256><<<NN * 64, 256, 0, stream>>>(a4, shw5, coef4);
        conv_ker<float, float, 64, 64, 16, 16, 1, 8><<<NN * BB * 2, 256, 0, stream>>>(a4, coef4, scw5, a5);
        stats_ker<float, 64, 256><<<NN * 64, 256, 0, stream>>>(a5, spool, coef5);
        pool_ker<float><<<NN * BB, 256, 0, stream>>>(a5, coef5, y);
    } else {
        bf16* a1 = (bf16*)(wsb + r1off);                        // 64 MiB region
        bf16* a2 = (bf16*)(wsb + r1off + (64ull << 20));        // 32 MiB region
        float* a3 = (float*)(wsb + r1off);
        float* a4 = (float*)(wsb + r1off + (64ull << 20));
        float* a5 = (float*)(wsb + r1off);

        fused01_ker<bf16><<<NN * BB * 8, 256, 0, stream>>>(sx, scw0, coef0, scw1, a1);
        stats_ker<bf16, 16, 4096><<<NN * 16, 256, 0, stream>>>(a1, shw2, coef1);
        conv_ker<bf16, bf16, 16, 32, 64, 32, 2, 4><<<NN * BB * 8, 256, 0, stream>>>(a1, coef1, scw2, a2);
        stats_ker<bf16, 32, 1024><<<NN * 32, 256, 0, stream>>>(a2, shw3, coef2);
        conv_ker<bf16, float, 32, 32, 32, 32, 1, 8><<<NN * BB * 4, 256, 0, stream>>>(a2, coef2, scw3, a3);
        stats_ker<float, 32, 1024><<<NN * 32, 256, 0, stream>>>(a3, shw4, coef3);
        conv_ker<float, float, 32, 64, 32, 16, 2, 4><<<NN * BB * 4, 256, 0, stream>>>(a3, coef3, scw4, a4);
        stats_ker<float, 64, 256><<<NN * 64, 256, 0, stream>>>(a4, shw5, coef4);
        conv_ker<float, float, 64, 64, 16, 16, 1, 8><<<NN * BB * 2, 256, 0, stream>>>(a4, coef4, scw5, a5);
        stats_ker<float, 64, 256><<<NN * 64, 256, 0, stream>>>(a5, spool, coef5);
        pool_ker<float><<<NN * BB, 256, 0, stream>>>(a5, coef5, y);
    }

    bn1_ker<<<NN, 256, 0, stream>>>(y, sg, sb, ybn);
    head_ker<<<BB, 256, 0, stream>>>(ybn, slin_w, slin_b, sjig_w, sjig_b, ograw, d_out, flag);
    ogbn_ker<<<1, 256, 0, stream>>>(ograw, d_out, flag);
}

// Round 4
// 1807.915 us; speedup vs baseline: 1.5356x; 1.5356x over previous
//
#include <hip/hip_runtime.h>
#include <hip/hip_bf16.h>

typedef __hip_bfloat16 bf16;

#define BB 32   // batch
#define NN 16   // patches / backbones

__device__ __forceinline__ float b2f(bf16 v){ return __bfloat162float(v); }
__device__ __forceinline__ bf16  f2b(float v){ return __float2bfloat16(v); }
__device__ __forceinline__ float ldv(const float* p){ return *p; }
__device__ __forceinline__ float ldv(const bf16* p){ return b2f(*p); }
__device__ __forceinline__ void  stv(float* p, float v){ *p = v; }
__device__ __forceinline__ void  stv(bf16* p, float v){ *p = f2b(v); }

// ---------------------------------------------------------------------------
// dtype probe: bf16 N(0,1) data never has exponent==0xFF; f32 data read as
// u16 halves virtually always does. flag=1 -> float32 inputs; 0 -> bf16.
// ---------------------------------------------------------------------------
__launch_bounds__(256)
__global__ void detect_ker(const unsigned short* __restrict__ xs, int* __restrict__ flag)
{
    int tid = threadIdx.x;
    int cnt = 0;
    for (int i = tid; i < 262144; i += 256) {
        unsigned short u = xs[i];
        if ((u & 0x7F80u) == 0x7F80u) cnt++;
    }
    #pragma unroll
    for (int off = 32; off > 0; off >>= 1) cnt += __shfl_down(cnt, off, 64);
    __shared__ int red[4];
    if ((tid & 63) == 0) red[tid >> 6] = cnt;
    __syncthreads();
    if (tid == 0) flag[0] = (red[0] + red[1] + red[2] + red[3]) > 0 ? 1 : 0;
}

// ---------------------------------------------------------------------------
// stage all inputs into a contiguous FLOAT arena (upconvert bf16 if needed)
// ---------------------------------------------------------------------------
struct CvtArgs { const void* src[19]; int cnt[19]; int off[19]; };

__launch_bounds__(256)
__global__ void convert_ker(CvtArgs a, float* __restrict__ dst, const int* __restrict__ flag)
{
    const int which = blockIdx.y;
    const int cnt = a.cnt[which];
    if ((int)blockIdx.x * 2048 >= cnt) return;
    const int base = blockIdx.x * 2048 + threadIdx.x;
    float* d = dst + a.off[which];
    if (*flag) {
        const float* s = (const float*)a.src[which];
        #pragma unroll
        for (int k = 0; k < 8; ++k) { int j = base + k * 256; if (j < cnt) d[j] = s[j]; }
    } else {
        const bf16* s = (const bf16*)a.src[which];
        #pragma unroll
        for (int k = 0; k < 8; ++k) { int j = base + k * 256; if (j < cnt) d[j] = b2f(s[j]); }
    }
}

// ---------------------------------------------------------------------------
// conv0 forward (recompute-only) + per-channel sum/sumsq atomics.
// accum[0..511]=sum, accum[512..1023]=sumsq per (n*16+c).
// ---------------------------------------------------------------------------
__launch_bounds__(256)
__global__ void conv0stats_ker(const float* __restrict__ x, const float* __restrict__ w,
                               float* __restrict__ accum)
{
    constexpr int STRIP = 8, STRIPS = 8, IN_ROWS = 10, TW = 66;
    __shared__ float tile[3][IN_ROWS][TW];
    const int tid = threadIdx.x;
    const int bid = blockIdx.x;
    const int s = bid % STRIPS;
    const int b = (bid / STRIPS) % BB;
    const int n = bid / (STRIPS * BB);
    const int pr = (n >> 2) * 64, pc = (n & 3) * 64;
    const int r0 = s * STRIP - 1;

    for (int idx = tid; idx < 3 * IN_ROWS * TW; idx += 256) {
        int ci = idx / (IN_ROWS * TW);
        int rem = idx - ci * (IN_ROWS * TW);
        int rr = rem / TW, cc = rem - rr * TW;
        int gr = r0 + rr, gc = cc - 1;
        float v = 0.f;
        if (gr >= 0 && gr < 64 && gc >= 0 && gc < 64)
            v = x[((size_t)(b * 3 + ci) * 256 + (pr + gr)) * 256 + (pc + gc)];
        tile[ci][rr][cc] = v;
    }
    __syncthreads();

    const int xo = tid & 63;
    const int cq = tid >> 6;
    for (int pass = 0; pass < 2; ++pass) {
        const int co = (pass * 4 + cq) * 2;
        const float* wb = w + (size_t)((n * 16 + co) * 3) * 9;
        float acc0[STRIP], acc1[STRIP];
        #pragma unroll
        for (int r = 0; r < STRIP; ++r) { acc0[r] = 0.f; acc1[r] = 0.f; }
        #pragma unroll
        for (int ci = 0; ci < 3; ++ci) {
            float w0[9], w1[9];
            #pragma unroll
            for (int j = 0; j < 9; ++j) {
                w0[j] = wb[ci * 9 + j];
                w1[j] = wb[(3 + ci) * 9 + j];
            }
            float win[3][3];
            #pragma unroll
            for (int c0 = 0; c0 < 3; ++c0) {
                win[0][c0] = tile[ci][0][xo + c0];
                win[1][c0] = tile[ci][1][xo + c0];
            }
            #pragma unroll
            for (int ry = 0; ry < STRIP; ++ry) {
                #pragma unroll
                for (int c0 = 0; c0 < 3; ++c0)
                    win[(ry + 2) % 3][c0] = tile[ci][ry + 2][xo + c0];
                #pragma unroll
                for (int ky = 0; ky < 3; ++ky)
                    #pragma unroll
                    for (int kx = 0; kx < 3; ++kx) {
                        float v = win[(ry + ky) % 3][kx];
                        acc0[ry] = fmaf(v, w0[ky * 3 + kx], acc0[ry]);
                        acc1[ry] = fmaf(v, w1[ky * 3 + kx], acc1[ry]);
                    }
            }
        }
        float s0 = 0.f, q0 = 0.f, s1 = 0.f, q1 = 0.f;
        #pragma unroll
        for (int r = 0; r < STRIP; ++r) {
            s0 += acc0[r]; q0 = fmaf(acc0[r], acc0[r], q0);
            s1 += acc1[r]; q1 = fmaf(acc1[r], acc1[r], q1);
        }
        #pragma unroll
        for (int off = 32; off > 0; off >>= 1) {
            s0 += __shfl_down(s0, off, 64); q0 += __shfl_down(q0, off, 64);
            s1 += __shfl_down(s1, off, 64); q1 += __shfl_down(q1, off, 64);
        }
        if (xo == 0) {
            atomicAdd(&accum[n * 16 + co],       s0);
            atomicAdd(&accum[512 + n * 16 + co], q0);
            atomicAdd(&accum[n * 16 + co + 1],       s1);
            atomicAdd(&accum[512 + n * 16 + co + 1], q1);
        }
    }
}

__launch_bounds__(256)
__global__ void coef0fin_ker(const float* __restrict__ accum, const float* __restrict__ hw,
                             float* __restrict__ coef)
{
    int i = threadIdx.x;            // n*16+c
    const float cnt = 131072.f;     // B * 64 * 64
    float mu = accum[i] / cnt;
    float var = fmaxf(accum[512 + i] / cnt - mu * mu, 0.f);
    float rs = rsqrtf(var + 1e-5f);
    int n = i >> 4, c = i & 15;
    float w0 = hw[(n * 3 + 0) * 16 + c];
    float w1 = hw[(n * 3 + 1) * 16 + c];
    float w2 = hw[(n * 3 + 2) * 16 + c];
    float c2 = w2 * 0.70710678118654752440f;
    coef[i * 3 + 0] = (w0 - c2) - w1 * rs * mu + c2 * rs * rs * mu * mu;
    coef[i * 3 + 1] = w1 * rs - 2.f * c2 * rs * rs * mu;
    coef[i * 3 + 2] = c2 * rs * rs;
}

// ---------------------------------------------------------------------------
// fused stage0+1: recompute conv0 tile from x (LDS), herpn(coef0), conv1 -> a1
// ---------------------------------------------------------------------------
template<typename TO>
__launch_bounds__(256)
__global__ void fused01_ker(const float* __restrict__ x, const float* __restrict__ w0g,
                            const float* __restrict__ coef, const float* __restrict__ w1g,
                            TO* __restrict__ aout)
{
    constexpr int STRIPS = 8;
    __shared__ float xt[3][12][68];
    __shared__ float a0t[16][10][66];
    __shared__ float wt[16 * 27];
    __shared__ float cfA[16], cfB[16], cfC[16];

    const int tid = threadIdx.x;
    const int bid = blockIdx.x;
    const int s = bid % STRIPS;
    const int b = (bid / STRIPS) % BB;
    const int n = bid / (STRIPS * BB);
    const int pr = (n >> 2) * 64, pc = (n & 3) * 64;

    if (tid < 16) {
        cfA[tid] = coef[(n * 16 + tid) * 3 + 0];
        cfB[tid] = coef[(n * 16 + tid) * 3 + 1];
        cfC[tid] = coef[(n * 16 + tid) * 3 + 2];
    }
    for (int i = tid; i < 16 * 27; i += 256) wt[i] = w0g[(size_t)n * 432 + i];

    const int rx0 = s * 8 - 2;
    for (int idx = tid; idx < 3 * 12 * 68; idx += 256) {
        int ci = idx / 816;
        int rem = idx - ci * 816;
        int rr = rem / 68, cc = rem - rr * 68;
        int gr = rx0 + rr, gc = cc - 2;
        float v = 0.f;
        if (gr >= 0 && gr < 64 && gc >= 0 && gc < 64)
            v = x[((size_t)(b * 3 + ci) * 256 + (pr + gr)) * 256 + (pc + gc)];
        xt[ci][rr][cc] = v;
    }
    __syncthreads();

    // herpn(conv0) tile; cells outside the 64x64 patch are conv1's zero pad
    for (int idx = tid; idx < 16 * 10 * 66; idx += 256) {
        int c = idx / 660;
        int rem = idx - c * 660;
        int rr = rem / 66, cc = rem - rr * 66;
        int gr = s * 8 - 1 + rr, gc = cc - 1;
        float v = 0.f;
        if (gr >= 0 && gr < 64 && gc >= 0 && gc < 64) {
            float acc = 0.f;
            const float* wp = &wt[c * 27];
            #pragma unroll
            for (int ci = 0; ci < 3; ++ci)
                #pragma unroll
                for (int ky = 0; ky < 3; ++ky)
                    #pragma unroll
                    for (int kx = 0; kx < 3; ++kx)
                        acc = fmaf(xt[ci][rr + ky][cc + kx], wp[ci * 9 + ky * 3 + kx], acc);
            v = fmaf(acc, fmaf(acc, cfC[c], cfB[c]), cfA[c]);
        }
        a0t[c][rr][cc] = v;
    }
    __syncthreads();

    const int xo = tid & 63;
    const int cq = tid >> 6;
    for (int pass = 0; pass < 2; ++pass) {
        const int co = (pass * 4 + cq) * 2;
        const float* wb = w1g + (size_t)((n * 16 + co) * 16) * 9;
        float acc0[8], acc1[8];
        #pragma unroll
        for (int r = 0; r < 8; ++r) { acc0[r] = 0.f; acc1[r] = 0.f; }
        for (int ci = 0; ci < 16; ++ci) {
            float w0[9], w1[9];
            #pragma unroll
            for (int j = 0; j < 9; ++j) {
                w0[j] = wb[ci * 9 + j];
                w1[j] = wb[(16 + ci) * 9 + j];
            }
            float win[3][3];
            #pragma unroll
            for (int c0 = 0; c0 < 3; ++c0) {
                win[0][c0] = a0t[ci][0][xo + c0];
                win[1][c0] = a0t[ci][1][xo + c0];
            }
            #pragma unroll
            for (int ry = 0; ry < 8; ++ry) {
                #pragma unroll
                for (int c0 = 0; c0 < 3; ++c0)
                    win[(ry + 2) % 3][c0] = a0t[ci][ry + 2][xo + c0];
                #pragma unroll
                for (int ky = 0; ky < 3; ++ky)
                    #pragma unroll
                    for (int kx = 0; kx < 3; ++kx) {
                        float v = win[(ry + ky) % 3][kx];
                        acc0[ry] = fmaf(v, w0[ky * 3 + kx], acc0[ry]);
                        acc1[ry] = fmaf(v, w1[ky * 3 + kx], acc1[ry]);
                    }
            }
        }
        TO* ob = aout + (size_t)((n * BB + b) * 16 + co) * 4096 + (s * 8) * 64 + xo;
        #pragma unroll
        for (int ry = 0; ry < 8; ++ry) {
            stv(&ob[ry * 64], acc0[ry]);
            stv(&ob[4096 + ry * 64], acc1[ry]);
        }
    }
}

// ---------------------------------------------------------------------------
// stats: per (n,c) mean/var over [B,HW]; fold HerPN into quadratic coef.
// ---------------------------------------------------------------------------
template<typename TI, int C, int HW>
__launch_bounds__(256)
__global__ void stats_ker(const TI* __restrict__ a, const float* __restrict__ hw,
                          float* __restrict__ coef)
{
    const int tid = threadIdx.x;
    const int n = blockIdx.x / C, c = blockIdx.x % C;
    float s = 0.f, s2 = 0.f;
    for (int b = 0; b < BB; ++b) {
        const TI* p = a + (size_t)((n * BB + b) * C + c) * HW;
        for (int i = tid; i < HW; i += 256) {
            float v = ldv(&p[i]);
            s += v;
            s2 = fmaf(v, v, s2);
        }
    }
    #pragma unroll
    for (int off = 32; off > 0; off >>= 1) {
        s  += __shfl_down(s, off, 64);
        s2 += __shfl_down(s2, off, 64);
    }
    __shared__ float red[8];
    int wid = tid >> 6, lane = tid & 63;
    if (lane == 0) { red[wid] = s; red[4 + wid] = s2; }
    __syncthreads();
    if (tid == 0) {
        s  = red[0] + red[1] + red[2] + red[3];
        s2 = red[4] + red[5] + red[6] + red[7];
        const float cnt = (float)(BB * HW);
        float mu = s / cnt;
        float var = fmaxf(s2 / cnt - mu * mu, 0.f);
        float rs = rsqrtf(var + 1e-5f);
        float w0 = hw[(n * 3 + 0) * C + c];
        float w1 = hw[(n * 3 + 1) * C + c];
        float w2 = hw[(n * 3 + 2) * C + c];
        float c2 = w2 * 0.70710678118654752440f;
        coef[(n * C + c) * 3 + 0] = (w0 - c2) - w1 * rs * mu + c2 * rs * rs * mu * mu;
        coef[(n * C + c) * 3 + 1] = w1 * rs - 2.f * c2 * rs * rs * mu;
        coef[(n * C + c) * 3 + 2] = c2 * rs * rs;
    }
}

// ---------------------------------------------------------------------------
// generic fused herpn+conv3x3
// ---------------------------------------------------------------------------
template<typename TI, typename TO, int CIN, int COUT, int WIN, int WOUT, int STRIDE, int STRIP>
__launch_bounds__(256)
__global__ void conv_ker(const TI* __restrict__ ain, const float* __restrict__ coef,
                         const float* __restrict__ w, TO* __restrict__ aout)
{
    constexpr int HIN = WIN, HOUT = WOUT;
    constexpr int STRIPS = HOUT / STRIP;
    constexpr int IN_ROWS = STRIDE * (STRIP - 1) + 3;
    constexpr int TW = WIN + 2;
    constexpr int CQ = 256 / WOUT;
    constexpr int TCO = 2;
    constexpr int PASSES = COUT / (CQ * TCO);

    __shared__ float tile[CIN][IN_ROWS][TW];
    __shared__ float cfA[CIN], cfB[CIN], cfC[CIN];

    const int tid = threadIdx.x;
    const int bid = blockIdx.x;
    const int s = bid % STRIPS;
    const int b = (bid / STRIPS) % BB;
    const int n = bid / (STRIPS * BB);

    if (tid < CIN) {
        cfA[tid] = coef[(n * CIN + tid) * 3 + 0];
        cfB[tid] = coef[(n * CIN + tid) * 3 + 1];
        cfC[tid] = coef[(n * CIN + tid) * 3 + 2];
    }
    __syncthreads();

    const int r0 = s * STRIP * STRIDE - 1;
    const TI* abase = ain + (size_t)(n * BB + b) * CIN * HIN * WIN;
    for (int idx = tid; idx < CIN * IN_ROWS * TW; idx += 256) {
        int ci = idx / (IN_ROWS * TW);
        int rem = idx - ci * (IN_ROWS * TW);
        int rr = rem / TW;
        int cc = rem - rr * TW;
        int gr = r0 + rr, gc = cc - 1;
        float v = 0.f;
        if (gr >= 0 && gr < HIN && gc >= 0 && gc < WIN) {
            float raw = ldv(&abase[(size_t)ci * HIN * WIN + gr * WIN + gc]);
            v = fmaf(raw, fmaf(raw, cfC[ci], cfB[ci]), cfA[ci]);
        }
        tile[ci][rr][cc] = v;
    }
    __syncthreads();

    const int xo = tid % WOUT;
    const int cq = tid / WOUT;
    #pragma unroll
    for (int pass = 0; pass < PASSES; ++pass) {
        const int co = (pass * CQ + cq) * TCO;
        const float* wb = w + (size_t)((n * COUT + co) * CIN) * 9;
        float acc0[STRIP], acc1[STRIP];
        #pragma unroll
        for (int r = 0; r < STRIP; ++r) { acc0[r] = 0.f; acc1[r] = 0.f; }
        for (int ci = 0; ci < CIN; ++ci) {
            float w0[9], w1[9];
            #pragma unroll
            for (int j = 0; j < 9; ++j) {
                w0[j] = wb[ci * 9 + j];
                w1[j] = wb[(CIN + ci) * 9 + j];
            }
            if (STRIDE == 1) {
                float win[3][3];
                #pragma unroll
                for (int c0 = 0; c0 < 3; ++c0) {
                    win[0][c0] = tile[ci][0][xo + c0];
                    win[1][c0] = tile[ci][1][xo + c0];
                }
                #pragma unroll
                for (int ry = 0; ry < STRIP; ++ry) {
                    #pragma unroll
                    for (int c0 = 0; c0 < 3; ++c0)
                        win[(ry + 2) % 3][c0] = tile[ci][ry + 2][xo + c0];
                    #pragma unroll
                    for (int ky = 0; ky < 3; ++ky)
                        #pragma unroll
                        for (int kx = 0; kx < 3; ++kx) {
                            float v = win[(ry + ky) % 3][kx];
                            acc0[ry] = fmaf(v, w0[ky * 3 + kx], acc0[ry]);
                            acc1[ry] = fmaf(v, w1[ky * 3 + kx], acc1[ry]);
                        }
                }
            } else {
                #pragma unroll
                for (int ry = 0; ry < STRIP; ++ry)
                    #pragma unroll
                    for (int ky = 0; ky < 3; ++ky)
                        #pragma unroll
                        for (int kx = 0; kx < 3; ++kx) {
                            float v = tile[ci][ry * 2 + ky][xo * 2 + kx];
                            acc0[ry] = fmaf(v, w0[ky * 3 + kx], acc0[ry]);
                            acc1[ry] = fmaf(v, w1[ky * 3 + kx], acc1[ry]);
                        }
            }
        }
        TO* ob = aout + (size_t)((n * BB + b) * COUT + co) * HOUT * WOUT
                 + (s * STRIP) * WOUT + xo;
        #pragma unroll
        for (int ry = 0; ry < STRIP; ++ry) {
            stv(&ob[ry * WOUT], acc0[ry]);
            stv(&ob[HOUT * WOUT + ry * WOUT], acc1[ry]);
        }
    }
}

// ---------------------------------------------------------------------------
// pool: herpn(a5) -> quadrant means -> y[N,B,256] (fp32)
// ---------------------------------------------------------------------------
template<typename TI>
__launch_bounds__(256)
__global__ void pool_ker(const TI* __restrict__ a5, const float* __restrict__ coef,
                         float* __restrict__ y)
{
    const int n = blockIdx.x / BB, b = blockIdx.x % BB;
    const int f = threadIdx.x;
    const int c = f >> 2, qh = (f >> 1) & 1, qw = f & 1;
    const TI* p = a5 + (size_t)((n * BB + b) * 64 + c) * 256;
    float A = coef[(n * 64 + c) * 3 + 0];
    float Bc = coef[(n * 64 + c) * 3 + 1];
    float Cc = coef[(n * 64 + c) * 3 + 2];
    float ssum = 0.f;
    for (int iy = 0; iy < 8; ++iy)
        for (int ix = 0; ix < 8; ++ix) {
            float raw = ldv(&p[(qh * 8 + iy) * 16 + (qw * 8 + ix)]);
            ssum += fmaf(raw, fmaf(raw, Cc, Bc), A);
        }
    y[(size_t)(n * BB + b) * 256 + f] = ssum * (1.f / 64.f);
}

// ---------------------------------------------------------------------------
// bn1: per (n,f) BN over B; writes batch-major yt[B][4096] for the head GEMM
// ---------------------------------------------------------------------------
__launch_bounds__(256)
__global__ void bn1_ker(const float* __restrict__ y, const float* __restrict__ g,
                        const float* __restrict__ bta, float* __restrict__ yt)
{
    const int gid = blockIdx.x * 256 + threadIdx.x;   // n*256 + f
    const int n = gid >> 8;
    float s = 0.f, s2 = 0.f;
    for (int b = 0; b < BB; ++b) {
        float v = y[(size_t)((n * BB + b) * 256) + (gid & 255)];
        s += v;
        s2 = fmaf(v, v, s2);
    }
    float mu = s * (1.f / BB);
    float var = fmaxf(s2 * (1.f / BB) - mu * mu, 0.f);
    float rs = rsqrtf(var + 1e-5f);
    float gg = g[gid];
    float bb = bta[gid];
    for (int b = 0; b < BB; ++b) {
        float v = y[(size_t)((n * BB + b) * 256) + (gid & 255)];
        yt[(size_t)b * 4096 + gid] = fmaf((v - mu) * rs, gg, bb);
    }
}

// ---------------------------------------------------------------------------
// og head: column-parallel GEMM. 256 blocks (one per output col j); lin_w row
// staged in LDS once; 4 waves x 8 batches, lane-split K + shuffle reduce.
// ---------------------------------------------------------------------------
__launch_bounds__(256)
__global__ void oghead_ker(const float* __restrict__ yt, const float* __restrict__ lin_w,
                           const float* __restrict__ lin_b, float* __restrict__ ograw)
{
    __shared__ float sw[4096];
    const int j = blockIdx.x;
    const float* wrow = lin_w + (size_t)j * 4096;
    for (int i = threadIdx.x; i < 4096; i += 256) sw[i] = wrow[i];
    __syncthreads();
    const int wv = threadIdx.x >> 6, ln = threadIdx.x & 63;
    const float bj = lin_b[j];
    for (int b = wv; b < BB; b += 4) {
        const float* yr = yt + (size_t)b * 4096;
        float a = 0.f;
        for (int i = ln; i < 4096; i += 64)
            a = fmaf(yr[i], sw[i], a);
        #pragma unroll
        for (int off = 32; off > 0; off >>= 1) a += __shfl_down(a, off, 64);
        if (ln == 0) ograw[b * 256 + j] = a + bj;
    }
}

// ---------------------------------------------------------------------------
// pred head: block = b*16+n; 16 k x 16-lane segmented dot over 256 features
// ---------------------------------------------------------------------------
__launch_bounds__(256)
__global__ void pred_ker(const float* __restrict__ yt, const float* __restrict__ jig_w,
                         const float* __restrict__ jig_b, void* __restrict__ d_out,
                         const int* __restrict__ flag)
{
    __shared__ float sy[256];
    const int b = blockIdx.x >> 4, n = blockIdx.x & 15;
    sy[threadIdx.x] = yt[(size_t)b * 4096 + n * 256 + threadIdx.x];
    __syncthreads();
    const int k = threadIdx.x >> 4, part = threadIdx.x & 15;
    const float* wrow = jig_w + k * 256 + part * 16;
    const float* srow = sy + part * 16;
    float p = 0.f;
    #pragma unroll
    for (int t = 0; t < 16; ++t) p = fmaf(srow[t], wrow[t], p);
    #pragma unroll
    for (int off = 8; off > 0; off >>= 1) p += __shfl_down(p, off, 16);
    if (part == 0) {
        float v = p + jig_b[k];
        int pidx = 8192 + (b * 16 + n) * 16 + k;
        if (*flag) ((float*)d_out)[pidx] = v;
        else       ((bf16*)d_out)[pidx] = f2b(v);
    }
}

__launch_bounds__(256)
__global__ void ogbn_ker(const float* __restrict__ ograw, void* __restrict__ d_out,
                         const int* __restrict__ flag)
{
    const int j = threadIdx.x;
    float s = 0.f, s2 = 0.f;
    for (int b = 0; b < BB; ++b) {
        float v = ograw[b * 256 + j];
        s += v;
        s2 = fmaf(v, v, s2);
    }
    float mu = s * (1.f / BB);
    float var = fmaxf(s2 * (1.f / BB) - mu * mu, 0.f);
    float rs = rsqrtf(var + 1e-5f);
    const bool isf32 = (*flag != 0);
    for (int b = 0; b < BB; ++b) {
        float v = (ograw[b * 256 + j] - mu) * rs;
        if (isf32) ((float*)d_out)[b * 256 + j] = v;
        else       ((bf16*)d_out)[b * 256 + j] = f2b(v);
    }
    float t = (float)(j & 15);
    if (isf32) { ((float*)d_out)[16384 + j] = t; ((float*)d_out)[16640 + j] = t; }
    else       { ((bf16*)d_out)[16384 + j] = f2b(t); ((bf16*)d_out)[16640 + j] = f2b(t); }
}

// ---------------------------------------------------------------------------
extern "C" void kernel_launch(void* const* d_in, const int* in_sizes, int n_in,
                              void* d_out, int out_size, void* d_ws, size_t ws_size,
                              hipStream_t stream)
{
    char* wsb = (char*)d_ws;
    int*   flag  = (int*)wsb;                       // @0
    float* accum = (float*)(wsb + 4096);            // 1024 f
    float* coefs = (float*)(wsb + 16384);           // 6*3072 f
    float* y     = (float*)(wsb + 98304);           // 131072 f
    float* yt    = (float*)(wsb + 622592);          // 131072 f  [B][4096]
    float* ograw = (float*)(wsb + 1146880);         // 8192 f
    float* staged = (float*)(wsb + 1310720);        // f32 arena

    CvtArgs ca;
    int off = 0, maxc = 0;
    for (int i = 0; i < 19; ++i) {
        ca.src[i] = d_in[i];
        ca.cnt[i] = in_sizes[i];
        ca.off[i] = off;
        off += in_sizes[i];
        if (in_sizes[i] > maxc) maxc = in_sizes[i];
    }
    float* sx      = staged + ca.off[0];
    float* scw0    = staged + ca.off[1];
    float* shw1    = staged + ca.off[2];
    float* scw1    = staged + ca.off[3];
    float* shw2    = staged + ca.off[4];
    float* scw2    = staged + ca.off[5];
    float* shw3    = staged + ca.off[6];
    float* scw3    = staged + ca.off[7];
    float* shw4    = staged + ca.off[8];
    float* scw4    = staged + ca.off[9];
    float* shw5    = staged + ca.off[10];
    float* scw5    = staged + ca.off[11];
    float* spool   = staged + ca.off[12];
    float* sg      = staged + ca.off[13];
    float* sb      = staged + ca.off[14];
    float* slin_w  = staged + ca.off[15];
    float* slin_b  = staged + ca.off[16];
    float* sjig_w  = staged + ca.off[17];
    float* sjig_b  = staged + ca.off[18];

    float* coef0 = coefs + 0 * 3072;
    float* coef1 = coefs + 1 * 3072;
    float* coef2 = coefs + 2 * 3072;
    float* coef3 = coefs + 3 * 3072;
    float* coef4 = coefs + 4 * 3072;
    float* coef5 = coefs + 5 * 3072;

    size_t stagedEnd = 1310720ull + (size_t)off * 4ull;
    size_t r1off = (stagedEnd + (1ull << 20)) & ~((1ull << 20) - 1ull);
    const bool planA = ws_size >= r1off + (128ull << 20) + (64ull << 20);

    detect_ker<<<1, 256, 0, stream>>>((const unsigned short*)d_in[0], flag);
    convert_ker<<<dim3((maxc + 2047) / 2048, 19), 256, 0, stream>>>(ca, staged, flag);

    hipMemsetAsync(accum, 0, 1024 * sizeof(float), stream);
    conv0stats_ker<<<NN * BB * 8, 256, 0, stream>>>(sx, scw0, accum);
    coef0fin_ker<<<1, 256, 0, stream>>>(accum, shw1, coef0);

    if (planA) {
        float* a1 = (float*)(wsb + r1off);                      // 128 MiB region
        float* a2 = (float*)(wsb + r1off + (128ull << 20));     // 64 MiB region
        float* a3 = a1;
        float* a4 = a2;
        float* a5 = a1;

        fused01_ker<float><<<NN * BB * 8, 256, 0, stream>>>(sx, scw0, coef0, scw1, a1);
        stats_ker<float, 16, 4096><<<NN * 16, 256, 0, stream>>>(a1, shw2, coef1);
        conv_ker<float, float, 16, 32, 64, 32, 2, 4><<<NN * BB * 8, 256, 0, stream>>>(a1, coef1, scw2, a2);
        stats_ker<float, 32, 1024><<<NN * 32, 256, 0, stream>>>(a2, shw3, coef2);
        conv_ker<float, float, 32, 32, 32, 32, 1, 8><<<NN * BB * 4, 256, 0, stream>>>(a2, coef2, scw3, a3);
        stats_ker<float, 32, 1024><<<NN * 32, 256, 0, stream>>>(a3, shw4, coef3);
        conv_ker<float, float, 32, 64, 32, 16, 2, 4><<<NN * BB * 4, 256, 0, stream>>>(a3, coef3, scw4, a4);
        stats_ker<float, 64, 256><<<NN * 64, 256, 0, stream>>>(a4, shw5, coef4);
        conv_ker<float, float, 64, 64, 16, 16, 1, 8><<<NN * BB * 2, 256, 0, stream>>>(a4, coef4, scw5, a5);
        stats_ker<float, 64, 256><<<NN * 64, 256, 0, stream>>>(a5, spool, coef5);
        pool_ker<float><<<NN * BB, 256, 0, stream>>>(a5, coef5, y);
    } else {
        bf16* a1 = (bf16*)(wsb + r1off);                        // 64 MiB region
        bf16* a2 = (bf16*)(wsb + r1off + (64ull << 20));        // 32 MiB region
        float* a3 = (float*)(wsb + r1off);
        float* a4 = (float*)(wsb + r1off + (64ull << 20));
        float* a5 = (float*)(wsb + r1off);

        fused01_ker<bf16><<<NN * BB * 8, 256, 0, stream>>>(sx, scw0, coef0, scw1, a1);
        stats_ker<bf16, 16, 4096><<<NN * 16, 256, 0, stream>>>(a1, shw2, coef1);
        conv_ker<bf16, bf16, 16, 32, 64, 32, 2, 4><<<NN * BB * 8, 256, 0, stream>>>(a1, coef1, scw2, a2);
        stats_ker<bf16, 32, 1024><<<NN * 32, 256, 0, stream>>>(a2, shw3, coef2);
        conv_ker<bf16, float, 32, 32, 32, 32, 1, 8><<<NN * BB * 4, 256, 0, stream>>>(a2, coef2, scw3, a3);
        stats_ker<float, 32, 1024><<<NN * 32, 256, 0, stream>>>(a3, shw4, coef3);
        conv_ker<float, float, 32, 64, 32, 16, 2, 4><<<NN * BB * 4, 256, 0, stream>>>(a3, coef3, scw4, a4);
        stats_ker<float, 64, 256><<<NN * 64, 256, 0, stream>>>(a4, shw5, coef4);
        conv_ker<float, float, 64, 64, 16, 16, 1, 8><<<NN * BB * 2, 256, 0, stream>>>(a4, coef4, scw5, a5);
        stats_ker<float, 64, 256><<<NN * 64, 256, 0, stream>>>(a5, spool, coef5);
        pool_ker<float><<<NN * BB, 256, 0, stream>>>(a5, coef5, y);
    }

    bn1_ker<<<NN, 256, 0, stream>>>(y, sg, sb, yt);
    oghead_ker<<<256, 256, 0, stream>>>(yt, slin_w, slin_b, ograw);
    pred_ker<<<BB * NN, 256, 0, stream>>>(yt, sjig_w, sjig_b, d_out, flag);
    ogbn_ker<<<1, 256, 0, stream>>>(ograw, d_out, flag);
}